// Round 5
// baseline (4931.624 us; speedup 1.0000x reference)
//
#include <hip/hip_runtime.h>
#include <cstdint>
#include <cstddef>

// RNNLayer: B=64, T=1024, IN=512, H=512, fp32 in/out.
// Phase 1: Wx = X @ W_w^T + (W_b + U_b)  (f16 MFMA GEMM) -> d_out.
// Phase 2: scan with MFMA. 4 WGs x 512 threads; each WG owns 16 batches on one CU.
//   Per step: H_new[16,512] = tanh(Wx + H_old @ U^T) via mfma_f32_16x16x32_f16.
//   U: 12 k-steps (k<384) as reg-resident B-fragments (192 VGPR/wave),
//      4 k-steps (k>=384) in 128KB XOR-swizzled LDS shared by all 8 waves.
//   H_old: 16KB XOR-swizzled LDS, single-buffered, 2 raw barriers/step.
// Round-4 bug: U-tail staging wrote only 128 of 256 bytes/row (i<8 instead of
// i<16) -> kk=13..15 B-frags read uninitialized LDS -> NaN. Fixed here.

#define T_STEPS 1024

using f16 = _Float16;
typedef f16  f16x2 __attribute__((ext_vector_type(2)));
typedef f16  f16x8 __attribute__((ext_vector_type(8)));
typedef float f32x4 __attribute__((ext_vector_type(4)));

static __device__ __forceinline__ f16x8 cvt8(float4 v0, float4 v1) {
    return (f16x8){ (f16)v0.x, (f16)v0.y, (f16)v0.z, (f16)v0.w,
                    (f16)v1.x, (f16)v1.y, (f16)v1.z, (f16)v1.w };
}

// ---------------------------------------------------------------------------
// Kernel 1: Wx GEMM (round-2 kernel; bias includes U_b).
// ---------------------------------------------------------------------------
__global__ __launch_bounds__(256, 2)
void gemm_wx(const float* __restrict__ X, const float* __restrict__ W,
             const float* __restrict__ Wb, const float* __restrict__ Ub,
             float* __restrict__ out) {
    __shared__ __align__(16) char Al[128 * 128];
    __shared__ __align__(16) char Bl[128 * 128];

    const int tid  = threadIdx.x;
    const int lane = tid & 63;
    const int wid  = tid >> 6;
    const int wm   = wid & 1;
    const int wn   = wid >> 1;
    const int m0   = blockIdx.x * 128;
    const int n0   = blockIdx.y * 128;

    f32x4 acc[4][4] = {};

    for (int kt = 0; kt < 512; kt += 64) {
        __syncthreads();
#pragma unroll
        for (int i = 0; i < 4; ++i) {
            const int id   = tid + i * 256;
            const int row  = id >> 3;
            const int slot = id & 7;
            const float4* pa = reinterpret_cast<const float4*>(
                X + (size_t)(m0 + row) * 512 + kt + slot * 8);
            const float4* pb = reinterpret_cast<const float4*>(
                W + (size_t)(n0 + row) * 512 + kt + slot * 8);
            f16x8 va = cvt8(pa[0], pa[1]);
            f16x8 vb = cvt8(pb[0], pb[1]);
            const int cb = (slot * 16) ^ ((row & 7) << 4);
            *reinterpret_cast<f16x8*>(Al + row * 128 + cb) = va;
            *reinterpret_cast<f16x8*>(Bl + row * 128 + cb) = vb;
        }
        __syncthreads();

#pragma unroll
        for (int kk = 0; kk < 2; ++kk) {
            f16x8 af[4], bf[4];
#pragma unroll
            for (int mi = 0; mi < 4; ++mi) {
                const int r  = wm * 64 + mi * 16 + (lane & 15);
                const int cb = (kk * 64 + ((lane >> 4) * 16)) ^ ((r & 7) << 4);
                af[mi] = *reinterpret_cast<const f16x8*>(Al + r * 128 + cb);
            }
#pragma unroll
            for (int ni = 0; ni < 4; ++ni) {
                const int r  = wn * 64 + ni * 16 + (lane & 15);
                const int cb = (kk * 64 + ((lane >> 4) * 16)) ^ ((r & 7) << 4);
                bf[ni] = *reinterpret_cast<const f16x8*>(Bl + r * 128 + cb);
            }
#pragma unroll
            for (int mi = 0; mi < 4; ++mi)
#pragma unroll
                for (int ni = 0; ni < 4; ++ni)
                    acc[mi][ni] = __builtin_amdgcn_mfma_f32_16x16x32_f16(
                        af[mi], bf[ni], acc[mi][ni], 0, 0, 0);
        }
    }

#pragma unroll
    for (int ni = 0; ni < 4; ++ni) {
        const int col  = n0 + wn * 64 + ni * 16 + (lane & 15);
        const float bias = Wb[col] + Ub[col];   // fold U_b into Wx
#pragma unroll
        for (int mi = 0; mi < 4; ++mi) {
            const int rowb = m0 + wm * 64 + mi * 16 + ((lane >> 4) * 4);
#pragma unroll
            for (int e = 0; e < 4; ++e)
                out[(size_t)(rowb + e) * 512 + col] = acc[mi][ni][e] + bias;
        }
    }
}

// ---------------------------------------------------------------------------
// Kernel 2: MFMA scan. Fragment layouts as validated by gemm_wx:
//   A-frag: row = lane&15, k = (lane>>4)*8 + e (8 contiguous f16)
//   B-frag: row(n) = lane&15, k same
//   D:      col(n) = lane&15, row(m) = (lane>>4)*4 + e
// ---------------------------------------------------------------------------
__global__ __launch_bounds__(512, 2)
void rnn_scan(float* __restrict__ out, const float* __restrict__ h0,
              const float* __restrict__ Uw) {
    __shared__ __align__(16) char Ul[512 * 256];   // U[n][k=384..512) f16, 128KB
    __shared__ __align__(16) char Hs[16 * 1024];   // H[m][k] f16, 16KB

    const int tid  = threadIdx.x;
    const int wid  = tid >> 6;       // wave 0..7
    const int lane = tid & 63;
    const int l15  = lane & 15;
    const int l4   = lane >> 4;
    const int n0w  = wid * 64;       // this wave's N-range (4 tiles of 16)
    const int b0   = blockIdx.x * 16;
    const int aswz = (l15 & 7) << 4;

    // ---- U tail (k in [384,512)) -> LDS, row n = tid, XOR-swizzled 16B chunks.
    // Full row: 128 f16 = 256 B = 16 chunks of 8 floats.
    {
        const float4* src = reinterpret_cast<const float4*>(Uw + (size_t)tid * 512 + 384);
        const int sw = (tid & 7) << 4;
#pragma unroll
        for (int i = 0; i < 16; ++i) {
            f16x8 w = cvt8(src[2 * i], src[2 * i + 1]);
            *reinterpret_cast<f16x8*>(Ul + tid * 256 + ((16 * i) ^ sw)) = w;
        }
    }

    // ---- U main (k<384) -> reg B-fragments: u[kk][nt], kk=0..11, nt=0..3.
    f16x8 u[12][4];
#pragma unroll
    for (int kk = 0; kk < 12; ++kk)
#pragma unroll
        for (int nt = 0; nt < 4; ++nt) {
            const float4* p = reinterpret_cast<const float4*>(
                Uw + (size_t)(n0w + nt * 16 + l15) * 512 + kk * 32 + l4 * 8);
            u[kk][nt] = cvt8(p[0], p[1]);
        }

    // ---- h_0 -> Hs (thread tid: batch m=tid>>5, 16-f16 chunk c=tid&31)
    {
        const int m = tid >> 5, c = tid & 31;
        const float4* p = reinterpret_cast<const float4*>(
            h0 + (size_t)(b0 + m) * 512 + c * 16);
        f16x8 w0 = cvt8(p[0], p[1]);
        f16x8 w1 = cvt8(p[2], p[3]);
        const int mb = m * 1024, sw = (m & 7) << 4;
        *reinterpret_cast<f16x8*>(Hs + mb + ((c * 32) ^ sw)) = w0;
        *reinterpret_cast<f16x8*>(Hs + mb + ((c * 32 + 16) ^ sw)) = w1;
    }

    // ---- Wx/out per-lane byte offsets, one per m-row e (batch m = l4*4+e).
    float* const outg = out + (size_t)b0 * (T_STEPS * 512);
    int offe[4];
#pragma unroll
    for (int e = 0; e < 4; ++e)
        offe[e] = ((l4 * 4 + e) * (T_STEPS * 512) + (n0w + l15)) * 4;

    __syncthreads();

    for (int t = 0; t < T_STEPS; ++t) {
        // Wx loads for this step (consumed ~600cy later at tanh).
        float wx[4][4];
#pragma unroll
        for (int e = 0; e < 4; ++e) {
            const float* pe = reinterpret_cast<const float*>(
                reinterpret_cast<const char*>(outg) + offe[e]);
#pragma unroll
            for (int nt = 0; nt < 4; ++nt)
                wx[nt][e] = pe[nt * 16];
        }

        // MFMA phase: acc[nt] += A(kk) * U(kk,nt) over 16 k-steps.
        f32x4 acc[4];
#pragma unroll
        for (int nt = 0; nt < 4; ++nt) acc[nt] = (f32x4){0.f, 0.f, 0.f, 0.f};
#pragma unroll
        for (int kk = 0; kk < 16; ++kk) {
            const f16x8 a = *reinterpret_cast<const f16x8*>(
                Hs + l15 * 1024 + ((kk * 64 + l4 * 16) ^ aswz));
            if (kk < 12) {
#pragma unroll
                for (int nt = 0; nt < 4; ++nt)
                    acc[nt] = __builtin_amdgcn_mfma_f32_16x16x32_f16(
                        a, u[kk][nt], acc[nt], 0, 0, 0);
            } else {
#pragma unroll
                for (int nt = 0; nt < 4; ++nt) {
                    const f16x8 bb = *reinterpret_cast<const f16x8*>(
                        Ul + (size_t)(n0w + nt * 16 + l15) * 256 +
                        (((kk - 12) * 64 + l4 * 16) ^ aswz));
                    acc[nt] = __builtin_amdgcn_mfma_f32_16x16x32_f16(
                        a, bb, acc[nt], 0, 0, 0);
                }
            }
        }

        // tanh + out stores (register/global only — safe before barrier B).
        float hv[4][4];
#pragma unroll
        for (int nt = 0; nt < 4; ++nt)
#pragma unroll
            for (int e = 0; e < 4; ++e) {
                const float aa = acc[nt][e] + wx[nt][e];   // U_b already in wx
                const float ax = fabsf(aa);
                const float ex = __expf(2.0f * ax);
                const float r1 = 1.0f - 2.0f / (ex + 1.0f);  // tanh(|aa|)
                hv[nt][e] = copysignf(r1, aa);
            }
#pragma unroll
        for (int e = 0; e < 4; ++e) {
            float* pe = reinterpret_cast<float*>(
                reinterpret_cast<char*>(outg) + offe[e]);
#pragma unroll
            for (int nt = 0; nt < 4; ++nt)
                pe[nt * 16] = hv[nt][e];
            offe[e] += 2048;
        }

        // Barrier B: every wave's A-frag ds_reads completed (operands must be
        // in VGPRs before each MFMA issues) -> safe to overwrite Hs after.
        __builtin_amdgcn_sched_barrier(0);
        __builtin_amdgcn_s_barrier();
        __builtin_amdgcn_sched_barrier(0);

        // H_t writes: lane holds D rows m=l4*4+e, col j=n0w+nt*16+l15; k=j.
#pragma unroll
        for (int nt = 0; nt < 4; ++nt) {
            const int j2 = 2 * (n0w + nt * 16 + l15);
#pragma unroll
            for (int e = 0; e < 4; ++e) {
                const int m = l4 * 4 + e;
                *reinterpret_cast<f16*>(Hs + m * 1024 + (j2 ^ ((m & 7) << 4))) =
                    (f16)hv[nt][e];
            }
        }

        // Barrier A': H_t writes drained & visible; do NOT drain vmcnt
        // (out stores stay in flight across steps).
        asm volatile("s_waitcnt lgkmcnt(0)" ::: "memory");
        __builtin_amdgcn_s_barrier();
        __builtin_amdgcn_sched_barrier(0);
    }
}

// ---------------------------------------------------------------------------
extern "C" void kernel_launch(void* const* d_in, const int* in_sizes, int n_in,
                              void* d_out, int out_size, void* d_ws, size_t ws_size,
                              hipStream_t stream) {
    const float* X  = (const float*)d_in[0];
    const float* h0 = (const float*)d_in[1];
    const float* Ww = (const float*)d_in[2];
    const float* Wb = (const float*)d_in[3];
    const float* Uw = (const float*)d_in[4];
    const float* Ub = (const float*)d_in[5];
    float* out = (float*)d_out;

    gemm_wx<<<dim3(512, 4), dim3(256), 0, stream>>>(X, Ww, Wb, Ub, out);
    rnn_scan<<<dim3(4), dim3(512), 0, stream>>>(out, h0, Uw);
}